// Round 3
// baseline (138.058 us; speedup 1.0000x reference)
//
#include <hip/hip_runtime.h>
#include <math.h>

#define LDIM 512
#define BDIM 64
#define NBLK 2048              // main-kernel blocks (8/CU, full occupancy)
#define NWAVE (NBLK * 4)       // 8192 waves
#define ROWS (BDIM * LDIM)     // 32768 rows total
#define RPW (ROWS / NWAVE)     // 4 rows per wave; row stride 8192 = 16 samples

__device__ __forceinline__ void accum4(const float4 xv, const float4 tv,
                                       int j0, int sl,
                                       float& A, float& P, float& Q) {
  const float xs[4] = {xv.x, xv.y, xv.z, xv.w};
  const float ts[4] = {tv.x, tv.y, tv.z, tv.w};
#pragma unroll
  for (int k = 0; k < 4; ++k) {
    const float on = (j0 + k < sl) ? 1.f : 0.f;   // column tail mask
    const float xx = xs[k];
    const float tt = ts[k] * on;
    const float ax = fabsf(xx);
    const float m  = __logf(1.f + __expf(-ax));   // log(1+e^-|x|)
    A += tt;
    P += tt * (fmaxf(-xx, 0.f) + m);              // t * softplus(-x)
    Q += (on - tt) * (fmaxf(xx, 0.f) + m);        // (1-t) * softplus(x)
  }
}

// part[(k*3+c)*NBLK + B] = block B's partial for sample (B>>7) + 16k, component c.
__global__ __launch_bounds__(256) void bce_main_kernel(
    const float* __restrict__ x, const float* __restrict__ t,
    const int* __restrict__ seq_lens, float* __restrict__ part) {
  __shared__ int sl_sh[BDIM];
  __shared__ float psum[4][RPW][3];
  const int wave = threadIdx.x >> 6;
  const int lane = threadIdx.x & 63;
  if (threadIdx.x < BDIM) sl_sh[threadIdx.x] = seq_lens[threadIdx.x];
  __syncthreads();

  const int gw = blockIdx.x * 4 + wave;          // global wave id
  const int i  = gw & (LDIM - 1);                // row index (same for all k)
  const int b0 = gw >> 9;                        // base sample (== blockIdx>>7)

#pragma unroll
  for (int k = 0; k < RPW; ++k) {
    const int b  = b0 + 16 * k;                  // 8192 rows = exactly 16 samples
    const int sl = sl_sh[b];
    float A = 0.f, P = 0.f, Q = 0.f;
    if (i < sl) {                                // wave-uniform branch
      const size_t base = ((size_t)b * LDIM + (size_t)i) * LDIM;
      const float4* __restrict__ x4 = (const float4*)(x + base);
      const float4* __restrict__ t4 = (const float4*)(t + base);
      const int nv = (sl + 3) >> 2;              // <=128 float4 columns
      const int v1 = lane, v2 = lane + 64;
      const bool h1 = v1 < nv, h2 = v2 < nv;
      float4 xv1, tv1, xv2, tv2;
      if (h1) { xv1 = x4[v1]; tv1 = t4[v1]; }    // both loads in flight
      if (h2) { xv2 = x4[v2]; tv2 = t4[v2]; }
      if (h1) accum4(xv1, tv1, v1 << 2, sl, A, P, Q);
      if (h2) accum4(xv2, tv2, v2 << 2, sl, A, P, Q);
#pragma unroll
      for (int off = 32; off; off >>= 1) {       // wave reduce
        A += __shfl_down(A, off);
        P += __shfl_down(P, off);
        Q += __shfl_down(Q, off);
      }
    }
    if (lane == 0) { psum[wave][k][0] = A; psum[wave][k][1] = P; psum[wave][k][2] = Q; }
  }
  __syncthreads();
  if (threadIdx.x < RPW * 3) {                   // 12 partials per block
    const int k = threadIdx.x / 3, c = threadIdx.x % 3;
    const float v = psum[0][k][c] + psum[1][k][c] + psum[2][k][c] + psum[3][k][c];
    part[(size_t)threadIdx.x * NBLK + blockIdx.x] = v;
  }
}

// 64 blocks (one per sample) x 64 threads: coalesced read of 128 partials x3.
__global__ __launch_bounds__(64) void bce_final_kernel(
    const float* __restrict__ part, const int* __restrict__ seq_lens,
    float* __restrict__ out) {
  const int s = blockIdx.x;
  const int lane = threadIdx.x;
  const int k = s >> 4, b0 = s & 15;             // s = b0 + 16k
  float v0, v1, v2;
  {
    const float* p0 = part + (size_t)(k * 3 + 0) * NBLK + b0 * 128;
    const float* p1 = part + (size_t)(k * 3 + 1) * NBLK + b0 * 128;
    const float* p2 = part + (size_t)(k * 3 + 2) * NBLK + b0 * 128;
    v0 = p0[lane] + p0[lane + 64];
    v1 = p1[lane] + p1[lane + 64];
    v2 = p2[lane] + p2[lane + 64];
  }
#pragma unroll
  for (int off = 32; off; off >>= 1) {
    v0 += __shfl_down(v0, off);
    v1 += __shfl_down(v1, off);
    v2 += __shfl_down(v2, off);
  }
  if (lane == 0) {
    const float sl = (float)seq_lens[s];
    const float tp = sl * sl;
    const float density = v0 / fmaxf(tp, 1.f);
    const float w = fminf(fmaxf(0.01f / (density + 1e-6f), 1.f), 50.f);
    const float ps = (w * v1 + v2) / fmaxf(tp, 1.f);
    atomicAdd(out, ps * (1.f / 64.f));
  }
}

extern "C" void kernel_launch(void* const* d_in, const int* in_sizes, int n_in,
                              void* d_out, int out_size, void* d_ws, size_t ws_size,
                              hipStream_t stream) {
  const float* x = (const float*)d_in[0];
  const float* t = (const float*)d_in[1];
  const int* seq_lens = (const int*)d_in[2];
  float* out = (float*)d_out;
  float* part = (float*)d_ws;                    // 12*2048 floats = 96 KB

  hipMemsetAsync(out, 0, sizeof(float), stream); // out accumulated via atomics

  bce_main_kernel<<<NBLK, 256, 0, stream>>>(x, t, seq_lens, part);
  bce_final_kernel<<<BDIM, 64, 0, stream>>>(part, seq_lens, out);
}

// Round 4
// 134.005 us; speedup vs baseline: 1.0303x; 1.0303x over previous
//
#include <hip/hip_runtime.h>
#include <math.h>

#define LDIM 512
#define BDIM 64
#define BLK_PER_S 32   // blocks per sample; 4 waves/block -> rows i0 in [0,128)

__device__ __forceinline__ void accum4(const float4 xv, const float4 tv,
                                       int j0, int sl,
                                       float& A, float& P, float& Q) {
  const float xs[4] = {xv.x, xv.y, xv.z, xv.w};
  const float ts[4] = {tv.x, tv.y, tv.z, tv.w};
#pragma unroll
  for (int k = 0; k < 4; ++k) {
    const float on = (j0 + k < sl) ? 1.f : 0.f;   // column tail mask
    const float xx = xs[k];
    const float tt = ts[k] * on;
    const float ax = fabsf(xx);
    const float m  = __logf(1.f + __expf(-ax));   // log(1+e^-|x|)
    A += tt;
    P += tt * (fmaxf(-xx, 0.f) + m);              // t * softplus(-x)
    Q += (on - tt) * (fmaxf(xx, 0.f) + m);        // (1-t) * softplus(x)
  }
}

// part[b*32 + xblk] = {A, P, Q, 0} partials. Every block writes its slot.
__global__ __launch_bounds__(256) void bce_main_kernel(
    const float* __restrict__ x, const float* __restrict__ t,
    const int* __restrict__ seq_lens, float4* __restrict__ part) {
  const int b    = blockIdx.y;
  const int xblk = blockIdx.x;
  const int sl   = seq_lens[b];
  const int wave = threadIdx.x >> 6;
  const int lane = threadIdx.x & 63;
  const int i0   = xblk * 4 + wave;              // 0..127; rows i0 + 128r
  const int nv   = (sl + 3) >> 2;                // float4 columns in prefix
  const size_t sbase = (size_t)b * (LDIM * LDIM);

  // ---- load phase: up to 16 independent exec-masked float4 loads ----
  float4 xv[4][2], tv[4][2];
  bool act[4][2];
#pragma unroll
  for (int r = 0; r < 4; ++r) {
    const int i = i0 + 128 * r;                  // <= 511 always: in-bounds
    const bool rowon = i < sl;
    const float4* __restrict__ xp = (const float4*)(x + sbase + (size_t)i * LDIM);
    const float4* __restrict__ tp = (const float4*)(t + sbase + (size_t)i * LDIM);
#pragma unroll
    for (int s = 0; s < 2; ++s) {
      const int v = lane + 64 * s;
      act[r][s] = rowon && (v < nv);
      if (act[r][s]) { xv[r][s] = xp[v]; tv[r][s] = tp[v]; }
    }
  }

  // ---- compute phase ----
  float A = 0.f, P = 0.f, Q = 0.f;
#pragma unroll
  for (int r = 0; r < 4; ++r) {
#pragma unroll
    for (int s = 0; s < 2; ++s) {
      if (act[r][s]) {
        accum4(xv[r][s], tv[r][s], (lane + 64 * s) << 2, sl, A, P, Q);
      }
    }
  }

  // ---- wave reduce + block combine ----
#pragma unroll
  for (int off = 32; off; off >>= 1) {
    A += __shfl_down(A, off);
    P += __shfl_down(P, off);
    Q += __shfl_down(Q, off);
  }
  __shared__ float sred[4][3];
  if (lane == 0) { sred[wave][0] = A; sred[wave][1] = P; sred[wave][2] = Q; }
  __syncthreads();
  if (threadIdx.x == 0) {
    float4 p;
    p.x = sred[0][0] + sred[1][0] + sred[2][0] + sred[3][0];
    p.y = sred[0][1] + sred[1][1] + sred[2][1] + sred[3][1];
    p.z = sred[0][2] + sred[1][2] + sred[2][2] + sred[3][2];
    p.w = 0.f;
    part[b * BLK_PER_S + xblk] = p;
  }
}

// One block, 256 threads: wave w covers part-chunks w*8..w*8+7 for sample=lane.
__global__ __launch_bounds__(256) void bce_final_kernel(
    const float4* __restrict__ part, const int* __restrict__ seq_lens,
    float* __restrict__ out) {
  __shared__ float psum[4][BDIM][3];
  const int w = threadIdx.x >> 6;
  const int lane = threadIdx.x & 63;   // sample index
  float A = 0.f, P = 0.f, Q = 0.f;
#pragma unroll
  for (int m = 0; m < 8; ++m) {
    const float4 p = part[lane * BLK_PER_S + w * 8 + m];
    A += p.x; P += p.y; Q += p.z;
  }
  psum[w][lane][0] = A; psum[w][lane][1] = P; psum[w][lane][2] = Q;
  __syncthreads();
  if (threadIdx.x < BDIM) {
    A = psum[0][lane][0] + psum[1][lane][0] + psum[2][lane][0] + psum[3][lane][0];
    P = psum[0][lane][1] + psum[1][lane][1] + psum[2][lane][1] + psum[3][lane][1];
    Q = psum[0][lane][2] + psum[1][lane][2] + psum[2][lane][2] + psum[3][lane][2];
    const float sl = (float)seq_lens[lane];
    const float tp = sl * sl;                     // >= 4096 > 0
    const float density = A / fmaxf(tp, 1.f);
    const float wgt = fminf(fmaxf(0.01f / (density + 1e-6f), 1.f), 50.f);
    float ps = (wgt * P + Q) / fmaxf(tp, 1.f);
#pragma unroll
    for (int off = 32; off; off >>= 1) ps += __shfl_down(ps, off);
    if (lane == 0) out[0] = ps * (1.f / 64.f);
  }
}

extern "C" void kernel_launch(void* const* d_in, const int* in_sizes, int n_in,
                              void* d_out, int out_size, void* d_ws, size_t ws_size,
                              hipStream_t stream) {
  const float* x = (const float*)d_in[0];
  const float* t = (const float*)d_in[1];
  const int* seq_lens = (const int*)d_in[2];
  float* out = (float*)d_out;
  float4* part = (float4*)d_ws;   // 64*32 float4 = 32 KB, fully overwritten

  dim3 grid(BLK_PER_S, BDIM);     // 32 x 64 = 2048 blocks
  bce_main_kernel<<<grid, 256, 0, stream>>>(x, t, seq_lens, part);
  bce_final_kernel<<<1, 256, 0, stream>>>(part, seq_lens, out);
}